// Round 10
// baseline (130.235 us; speedup 1.0000x reference)
//
#include <hip/hip_runtime.h>

#define B_ 4
#define S_ 512
#define T_ 512
#define D_ 256
#define NSRC (B_ * S_)            // 2048 source rows
#define NROW 4096                 // src rows + tgt rows
#define K2F 2.8853900817779268f   // 2*log2(e): exp2(x*K2F) = e^(2x)

typedef __attribute__((ext_vector_type(8))) short short8;   // 8 bf16
typedef __attribute__((ext_vector_type(4))) float f32x4;
typedef __attribute__((ext_vector_type(2))) float f32x2;

__device__ __forceinline__ unsigned short f2bf(float f) {
    union { float f; unsigned u; } v; v.f = f;
    unsigned r = v.u + 0x7FFF + ((v.u >> 16) & 1);   // RNE
    return (unsigned short)(r >> 16);
}

// ---------------------------------------------------------------------------
// K1: ysyt+prob (VERBATIM R9, proven). 768 blocks x 256 thr.
//  blocks 0..255: ysyt with per-block W-slab LDS transpose; writes
//                 yst[d][global_row] f32 (transposed, free via MFMA D-layout).
//  blocks 256..767: prob softmax, 4 rows each.
// ---------------------------------------------------------------------------
__global__ __launch_bounds__(256) void ysyt_kernel(
    const float* __restrict__ src, const float* __restrict__ tgt,
    const float* __restrict__ Wsrc, const float* __restrict__ Wtgt,
    const float* __restrict__ Wp,  const float* __restrict__ bp,
    const float* __restrict__ bsrc, const float* __restrict__ btgt,
    float* __restrict__ yst, float* __restrict__ out)
{
    __shared__ unsigned short lwt[16384];    // 32 KB
    const int bid = blockIdx.x, tid = threadIdx.x;
    const int lane = tid & 63, w = tid >> 6;

    if (bid < 256) {
        const int rowblk = bid >> 2, colq = bid & 3;
        const int R0 = rowblk * 64;
        const int n = lane & 15, quad = lane >> 4;
        const int mat = (R0 >= NSRC) ? 1 : 0;
        const float* bias = mat ? btgt : bsrc;
        const float* Wm = mat ? Wtgt : Wsrc;
        const float* xb = mat ? &tgt[(R0 - NSRC) * D_] : &src[R0 * D_];

        {
            const int r = tid;
            const int ksr = r >> 5, qr = (r >> 3) & 3, jr = r & 7;
            const int wbase = ksr * 512 + qr * 8 + jr;
            #pragma unroll 4
            for (int i = 0; i < 16; i++) {
                float4 v = *(const float4*)&Wm[r * D_ + colq * 64 + 4 * i];
                const int cc = 4 * i;
                lwt[((cc + 0) >> 4) * 4096 + ((cc + 0) & 15) * 32 + wbase] = f2bf(v.x);
                lwt[((cc + 1) >> 4) * 4096 + ((cc + 1) & 15) * 32 + wbase] = f2bf(v.y);
                lwt[((cc + 2) >> 4) * 4096 + ((cc + 2) & 15) * 32 + wbase] = f2bf(v.z);
                lwt[((cc + 3) >> 4) * 4096 + ((cc + 3) & 15) * 32 + wbase] = f2bf(v.w);
            }
        }

        short8 af[8];
        #pragma unroll
        for (int ks = 0; ks < 8; ks++) {
            const float* p = &xb[(w * 16 + n) * D_ + ks * 32 + quad * 8];
            float4 u0 = *(const float4*)p;
            float4 u1 = *(const float4*)(p + 4);
            short8 v;
            v[0] = (short)f2bf(u0.x); v[1] = (short)f2bf(u0.y);
            v[2] = (short)f2bf(u0.z); v[3] = (short)f2bf(u0.w);
            v[4] = (short)f2bf(u1.x); v[5] = (short)f2bf(u1.y);
            v[6] = (short)f2bf(u1.z); v[7] = (short)f2bf(u1.w);
            af[ks] = v;
        }
        __syncthreads();

        #pragma unroll
        for (int gc = 0; gc < 4; gc++) {
            const int gcol = colq * 4 + gc;
            const unsigned short* bp2 = &lwt[gc * 4096 + n * 32 + quad * 8];
            short8 bf[8];
            #pragma unroll
            for (int ks = 0; ks < 8; ks++) bf[ks] = *(const short8*)&bp2[ks * 512];
            f32x4 a4 = {0.f, 0.f, 0.f, 0.f};
            #pragma unroll
            for (int ks = 0; ks < 8; ks++)
                a4 = __builtin_amdgcn_mfma_f32_16x16x32_bf16(af[ks], bf[ks], a4, 0, 0, 0);
            const float bv = bias[gcol * 16 + n];
            float4 o;
            o.x = __builtin_amdgcn_exp2f((a4[0] + bv) * K2F);
            o.y = __builtin_amdgcn_exp2f((a4[1] + bv) * K2F);
            o.z = __builtin_amdgcn_exp2f((a4[2] + bv) * K2F);
            o.w = __builtin_amdgcn_exp2f((a4[3] + bv) * K2F);
            *(float4*)&yst[(gcol * 16 + n) * NROW + R0 + w * 16 + quad * 4] = o;
        }
    } else {
        int row  = (bid - 256) * 4 + w;
        float p0 = 0.f, p1 = 0.f;
        #pragma unroll
        for (int i = 0; i < 4; i++) {
            int d = lane + i * 64;
            float v = tgt[row * D_ + d];
            float2 wv = *(const float2*)&Wp[d * 2];
            p0 = fmaf(v, wv.x, p0);
            p1 = fmaf(v, wv.y, p1);
        }
        #pragma unroll
        for (int off = 32; off > 0; off >>= 1) {
            p0 += __shfl_down(p0, off, 64);
            p1 += __shfl_down(p1, off, 64);
        }
        if (lane == 0) {
            const float L2E = 1.4426950408889634f;
            float l0 = p0 + bp[0], l1 = p1 + bp[1];
            float e10 = __builtin_amdgcn_exp2f((l1 - l0) * L2E);
            float e01 = __builtin_amdgcn_exp2f((l0 - l1) * L2E);
            out[B_ * T_ * S_ + row * 2 + 0] = __builtin_amdgcn_rcpf(1.f + e10);
            out[B_ * T_ * S_ + row * 2 + 1] = __builtin_amdgcn_rcpf(1.f + e01);
        }
    }
}

// ---------------------------------------------------------------------------
// K2: genp v5 — ZERO-LDS, ZERO-BARRIER streaming consumer.
// R7 lesson: v1/v3 both ~30us, 1.5x above the 20.5us LDS-issue floor ->
// stall-bound on staging/barriers, not LDS issue. yst (4MB) fits per-XCD L2
// -> read it DIRECTLY (Common-mistake #7: don't LDS-stage L2-resident data).
// Tile 64s x 32t x 128d; grid (8,16,8) with z = b*2+dhalf -> 1024 blocks =
// 4 blk/CU = 16 waves/CU, fully independent (no __syncthreads at all).
// Thread (m=tid&15, g=tid>>4): s = s0+4m.. (float4 reads, 256B/wave
// contiguous), t = t0+2g,2g+1 (float2, 4 addrs/wave, merged). Register
// double-buffer of 4-d groups; proven 4-term rcp fold. d-halves combine via
// unsafeAtomicAdd (out memset-0 by harness; dh0 adds C0-2*p0, dh1 adds
// -2*p1 -- order-independent). C0 per-wave via shfl_xor butterfly (no LDS).
// genP = C0 - 2 * sum_d w_d / (1 + ys*yt),  C0 = sum w + b_res.
// ---------------------------------------------------------------------------
__global__ __launch_bounds__(256) void genp_kernel(
    const float* __restrict__ yst,   // [256][4096]
    const float* __restrict__ Wres, const float* __restrict__ bres,
    float* __restrict__ out)
{
    const int tid = threadIdx.x;
    const int lane = tid & 63;
    const int s0 = blockIdx.x * 64;
    const int t0 = blockIdx.y * 32;
    const int b  = blockIdx.z >> 1;
    const int dh = blockIdx.z & 1;
    const int m  = tid & 15;             // s = s0 + 4m .. 4m+3
    const int g  = tid >> 4;             // t = t0 + 2g, 2g+1

    const int scol = b * S_ + s0 + 4 * m;          // col of this thread's 4 s
    const int tcol = NSRC + b * T_ + t0 + 2 * g;   // col of this thread's 2 t
    const int dbase = dh * 128;

    f32x2 acc[2][2];                     // [t-idx i][s-pair jp]
    acc[0][0] = (f32x2){0.f, 0.f}; acc[0][1] = (f32x2){0.f, 0.f};
    acc[1][0] = (f32x2){0.f, 0.f}; acc[1][1] = (f32x2){0.f, 0.f};
    const f32x2 one2 = {1.f, 1.f};

    #define KQLOAD(AS, AT, DQ) do {                                          \
        _Pragma("unroll")                                                    \
        for (int k = 0; k < 4; k++) {                                        \
            AS[k] = *(const float4*)&yst[(size_t)((DQ) + k) * NROW + scol];  \
            AT[k] = *(const float2*)&yst[(size_t)((DQ) + k) * NROW + tcol];  \
        }                                                                    \
    } while (0)

    #define KQBODY(AS, AT, DQ) do {                                          \
        const float w0 = Wres[(DQ) + 0], w1 = Wres[(DQ) + 1];                \
        const float w2 = Wres[(DQ) + 2], w3 = Wres[(DQ) + 3];                \
        const f32x2 wv0 = {w0, w0}, wv1 = {w1, w1};                          \
        const f32x2 wv2 = {w2, w2}, wv3 = {w3, w3};                          \
        _Pragma("unroll")                                                    \
        for (int i = 0; i < 2; i++) {                                        \
            const float c0 = i ? AT[0].y : AT[0].x;                          \
            const float c1 = i ? AT[1].y : AT[1].x;                          \
            const float c2 = i ? AT[2].y : AT[2].x;                          \
            const float c3 = i ? AT[3].y : AT[3].x;                          \
            const f32x2 c0v = {c0, c0}, c1v = {c1, c1};                      \
            const f32x2 c2v = {c2, c2}, c3v = {c3, c3};                      \
            _Pragma("unroll")                                                \
            for (int jp = 0; jp < 2; jp++) {                                 \
                const f32x2 a0 = jp ? (f32x2){AS[0].z, AS[0].w}              \
                                    : (f32x2){AS[0].x, AS[0].y};             \
                const f32x2 a1 = jp ? (f32x2){AS[1].z, AS[1].w}              \
                                    : (f32x2){AS[1].x, AS[1].y};             \
                const f32x2 a2 = jp ? (f32x2){AS[2].z, AS[2].w}              \
                                    : (f32x2){AS[2].x, AS[2].y};             \
                const f32x2 a3 = jp ? (f32x2){AS[3].z, AS[3].w}              \
                                    : (f32x2){AS[3].x, AS[3].y};             \
                f32x2 dd0 = a0 * c0v + one2;                                 \
                f32x2 dd1 = a1 * c1v + one2;                                 \
                f32x2 dd2 = a2 * c2v + one2;                                 \
                f32x2 dd3 = a3 * c3v + one2;                                 \
                f32x2 p01 = dd0 * dd1;                                       \
                f32x2 p23 = dd2 * dd3;                                       \
                f32x2 den = p01 * p23;                                       \
                f32x2 u01 = dd1 * wv0; u01 = dd0 * wv1 + u01;                \
                f32x2 u23 = dd3 * wv2; u23 = dd2 * wv3 + u23;                \
                f32x2 num = u01 * p23; num = u23 * p01 + num;                \
                f32x2 r;                                                     \
                r.x = __builtin_amdgcn_rcpf(den.x);                          \
                r.y = __builtin_amdgcn_rcpf(den.y);                          \
                acc[i][jp] = num * r + acc[i][jp];                           \
            }                                                                \
        }                                                                    \
    } while (0)

    float4 sA[4], sB[4];
    float2 tA[4], tB[4];
    KQLOAD(sA, tA, dbase);
    for (int it = 0; it < 16; it++) {     // each iter: 8 d (two 4-d groups)
        const int dq = dbase + it * 8;
        KQLOAD(sB, tB, dq + 4);
        KQBODY(sA, tA, dq);
        if (it < 15) KQLOAD(sA, tA, dq + 8);
        KQBODY(sB, tB, dq + 4);
    }
    #undef KQLOAD
    #undef KQBODY

    // C0 per-wave (butterfly -> all lanes), added only by the dh=0 half
    float cw = Wres[lane] + Wres[lane + 64] + Wres[lane + 128] + Wres[lane + 192];
    #pragma unroll
    for (int off = 32; off > 0; off >>= 1) cw += __shfl_xor(cw, off, 64);
    const float C0 = (dh == 0) ? (cw + bres[0]) : 0.f;

    #pragma unroll
    for (int i = 0; i < 2; i++) {
        float* orow = &out[(size_t)(b * T_ + t0 + 2 * g + i) * S_ + s0 + 4 * m];
        #pragma unroll
        for (int jp = 0; jp < 2; jp++) {
            unsafeAtomicAdd(&orow[2 * jp + 0], C0 - 2.f * acc[i][jp].x);
            unsafeAtomicAdd(&orow[2 * jp + 1], C0 - 2.f * acc[i][jp].y);
        }
    }
}

extern "C" void kernel_launch(void* const* d_in, const int* in_sizes, int n_in,
                              void* d_out, int out_size, void* d_ws, size_t ws_size,
                              hipStream_t stream) {
    const float* source = (const float*)d_in[0];
    const float* target = (const float*)d_in[1];
    const float* W_src  = (const float*)d_in[2];
    const float* b_src  = (const float*)d_in[3];
    const float* W_tgt  = (const float*)d_in[4];
    const float* b_tgt  = (const float*)d_in[5];
    const float* W_res  = (const float*)d_in[6];
    const float* b_res  = (const float*)d_in[7];
    const float* W_prob = (const float*)d_in[8];
    const float* b_prob = (const float*)d_in[9];
    float* out = (float*)d_out;

    float* yst = (float*)d_ws;                 // [256][4096] f32 = 4 MB

    ysyt_kernel<<<768, 256, 0, stream>>>(source, target, W_src, W_tgt,
                                         W_prob, b_prob, b_src, b_tgt,
                                         yst, out);
    genp_kernel<<<dim3(8, 16, 8), 256, 0, stream>>>(yst, W_res, b_res, out);
}